// Round 4
// baseline (136.544 us; speedup 1.0000x reference)
//
#include <hip/hip_runtime.h>
#include <hip/hip_bf16.h>
#include <stdint.h>
#include <stddef.h>

// Attention B=256,H=32,S=16,D=64: softmax(QK^T/sqrt(8) + ones) with JAX
// threefry dropout p=0.3 (key 42), then @V.
// R4: swapped QK^T (S^T = mfma(K,Q)) -> 4-shfl softmax; bf16 LDS staging via
// cvt_pk; no barriers (per-wave LDS); threefry hoisted under load latency.
// R5: occupancy x2. Back to 1 head/wave (R0 shape = 56 VGPR) keeping all R4
// wins. __launch_bounds__(256,8) -> VGPR cap 64 -> 8 waves/SIMD = 32 waves/CU
// (vs 16). Grid 2048, LDS 11776 B/block (8 blocks/CU fit). Halves per-wave
// critical path, doubles latency hiding; kernel was ~2x above memory roofline
// on pure stall time.

typedef __attribute__((ext_vector_type(8))) short short8;
typedef __attribute__((ext_vector_type(4))) float f32x4;
typedef __attribute__((ext_vector_type(4))) unsigned int u32x4;

#define VST 68  // V tile row stride (shorts): 8B-aligned rows, reads ~conflict-free
#define PST 24  // P tile row stride (shorts): 16B-aligned b128 frag reads

// packed f32x2 -> bf16x2, RNE via v_cvt_pk_bf16_f32 (compiler-generated)
__device__ __forceinline__ unsigned pk2_bf16(float a, float b) {
  float2 t; t.x = a; t.y = b;
  __hip_bfloat162 h = __float22bfloat162_rn(t);
  unsigned r;
  __builtin_memcpy(&r, &h, 4);
  return r;
}

// JAX threefry2x32, key=(0,42), counter (0, idx); draw = x0^x1. Bit-exact vs
// jax.random.bernoulli(jax.random.key(42), ...) — verified R0 (absmax 0.031).
__device__ __forceinline__ unsigned threefry_bits(unsigned idx) {
  const unsigned k0 = 0u, k1 = 42u;
  const unsigned k2 = k0 ^ k1 ^ 0x1BD11BDAu;
  unsigned x0 = k0;
  unsigned x1 = idx + k1;
#define TF_ROUND(r) { x0 += x1; x1 = (x1 << (r)) | (x1 >> (32 - (r))); x1 ^= x0; }
  TF_ROUND(13) TF_ROUND(15) TF_ROUND(26) TF_ROUND(6)
  x0 += k1; x1 += k2 + 1u;
  TF_ROUND(17) TF_ROUND(29) TF_ROUND(16) TF_ROUND(24)
  x0 += k2; x1 += k0 + 2u;
  TF_ROUND(13) TF_ROUND(15) TF_ROUND(26) TF_ROUND(6)
  x0 += k0; x1 += k1 + 3u;
  TF_ROUND(17) TF_ROUND(29) TF_ROUND(16) TF_ROUND(24)
  x0 += k1; x1 += k2 + 4u;
  TF_ROUND(13) TF_ROUND(15) TF_ROUND(26) TF_ROUND(6)
  x0 += k2; x1 += k0 + 5u;
#undef TF_ROUND
  return x0 ^ x1;
}

// mask for element idx = bh*256 + base + t, t=0..3 (value includes 1/0.7 scale)
__device__ __forceinline__ void drop_mask(int bh, int base, float* m) {
#pragma unroll
  for (int t = 0; t < 4; t++) {
    unsigned idx = ((unsigned)bh << 8) + (unsigned)(base + t);
    unsigned bits = threefry_bits(idx);
    float u = __builtin_bit_cast(float, 0x3F800000u | (bits >> 9)) - 1.0f;
    m[t] = (u < 0.7f) ? (1.0f / 0.7f) : 0.0f;
  }
}

// 8 f32 -> hi/lo bf16 split via cvt_pk pairs (~3 ops/elem vs ~12 bitwise)
__device__ __forceinline__ void cvt_hilo_f4(float4 a, float4 b, short8& hi, short8& lo) {
  float x[8] = {a.x, a.y, a.z, a.w, b.x, b.y, b.z, b.w};
  u32x4 hw, lw;
#pragma unroll
  for (int i = 0; i < 4; i++) {
    float e0 = x[2 * i], e1 = x[2 * i + 1];
    unsigned hp = pk2_bf16(e0, e1);
    float h0 = __builtin_bit_cast(float, hp << 16);
    float h1 = __builtin_bit_cast(float, hp & 0xFFFF0000u);
    unsigned lp = pk2_bf16(e0 - h0, e1 - h1);
    hw[i] = hp; lw[i] = lp;
  }
  hi = __builtin_bit_cast(short8, hw);
  lo = __builtin_bit_cast(short8, lw);
}

__global__ __launch_bounds__(256, 8) void attn_kernel(
    const float* __restrict__ q, const float* __restrict__ k,
    const float* __restrict__ v, float* __restrict__ out) {
  // per-wave LDS (no cross-wave sharing -> no barriers needed)
  __shared__ __align__(16) unsigned short vst[4][16 * VST];  // 8704 B
  __shared__ __align__(16) unsigned short pst[4][16 * PST];  // 3072 B

  const int lane = threadIdx.x & 63;
  const int w = threadIdx.x >> 6;
  const int bh = blockIdx.x * 4 + w;   // 0..8191, one head per wave
  const int c = lane & 15;             // frag row; with swapped QK^T: q-row
  const int g = lane >> 4;             // quad

  // ---- issue all loads up front ----
  const float4* qr = (const float4*)(q + (size_t)bh * 1024 + c * 64 + g * 8);
  const float4* kr = (const float4*)(k + (size_t)bh * 1024 + c * 64 + g * 8);
  float4 qv0 = qr[0], qv1 = qr[1], qv2 = qr[8], qv3 = qr[9];
  float4 kv0 = kr[0], kv1 = kr[1], kv2 = kr[8], kv3 = kr[9];
  const float4* vs = (const float4*)(v + (size_t)bh * 1024);
  float4 vt0 = vs[lane], vt1 = vs[64 + lane], vt2 = vs[128 + lane], vt3 = vs[192 + lane];

  // ---- dropout mask: data-independent VALU, runs under load latency ----
  // swapped layout: lane(c,g) reg t holds element (row=c, col=4g+t)
  float m[4];
  drop_mask(bh, (c << 4) + 4 * g, m);

  // ---- Q/K hi/lo bf16 split ----
  short8 qhi0, qlo0, qhi1, qlo1, khi0, klo0, khi1, klo1;
  cvt_hilo_f4(qv0, qv1, qhi0, qlo0);
  cvt_hilo_f4(qv2, qv3, qhi1, qlo1);
  cvt_hilo_f4(kv0, kv1, khi0, klo0);
  cvt_hilo_f4(kv2, kv3, khi1, klo1);

  // ---- S^T = K Q^T (swapped operands): hi*hi + lo*hi + hi*lo ----
  // acc[t] = S[c][4g+t] -> q-row c is in-lane across regs t and quads g.
  f32x4 acc = {0.f, 0.f, 0.f, 0.f};
  acc = __builtin_amdgcn_mfma_f32_16x16x32_bf16(khi0, qhi0, acc, 0, 0, 0);
  acc = __builtin_amdgcn_mfma_f32_16x16x32_bf16(khi1, qhi1, acc, 0, 0, 0);
  acc = __builtin_amdgcn_mfma_f32_16x16x32_bf16(klo0, qhi0, acc, 0, 0, 0);
  acc = __builtin_amdgcn_mfma_f32_16x16x32_bf16(klo1, qhi1, acc, 0, 0, 0);
  acc = __builtin_amdgcn_mfma_f32_16x16x32_bf16(khi0, qlo0, acc, 0, 0, 0);
  acc = __builtin_amdgcn_mfma_f32_16x16x32_bf16(khi1, qlo1, acc, 0, 0, 0);

  // ---- row softmax: 3 VALU + 2 shfl for max, same for sum ----
  // +ones mask cancels in softmax.
  const float SCALE = 0.35355339059327373f;
  float sv[4];
#pragma unroll
  for (int t = 0; t < 4; t++) sv[t] = acc[t] * SCALE;
  float mx = fmaxf(fmaxf(sv[0], sv[1]), fmaxf(sv[2], sv[3]));
  mx = fmaxf(mx, __shfl_xor(mx, 16));
  mx = fmaxf(mx, __shfl_xor(mx, 32));
  float p0 = __expf(sv[0] - mx), p1 = __expf(sv[1] - mx);
  float p2v = __expf(sv[2] - mx), p3 = __expf(sv[3] - mx);
  float sum = (p0 + p1) + (p2v + p3);
  sum += __shfl_xor(sum, 16);
  sum += __shfl_xor(sum, 32);
  float rs = 1.0f / sum;
  float ad[4] = {p0 * rs * m[0], p1 * rs * m[1], p2v * rs * m[2], p3 * rs * m[3]};

  // ---- stage V as bf16 (cvt_pk at write). lane holds V[4p+g][4c..4c+3] ----
  unsigned short* vw = &vst[w][0];
  {
    float4 vv;
    unsigned w0, w1;
    vv = vt0; w0 = pk2_bf16(vv.x, vv.y); w1 = pk2_bf16(vv.z, vv.w);
    *(uint2*)(&vw[(0 + g) * VST + 4 * c]) = make_uint2(w0, w1);
    vv = vt1; w0 = pk2_bf16(vv.x, vv.y); w1 = pk2_bf16(vv.z, vv.w);
    *(uint2*)(&vw[(4 + g) * VST + 4 * c]) = make_uint2(w0, w1);
    vv = vt2; w0 = pk2_bf16(vv.x, vv.y); w1 = pk2_bf16(vv.z, vv.w);
    *(uint2*)(&vw[(8 + g) * VST + 4 * c]) = make_uint2(w0, w1);
    vv = vt3; w0 = pk2_bf16(vv.x, vv.y); w1 = pk2_bf16(vv.z, vv.w);
    *(uint2*)(&vw[(12 + g) * VST + 4 * c]) = make_uint2(w0, w1);
  }

  // ---- stage P as bf16: one 8B packed write (row c, cols 4g..4g+3) ----
  unsigned short* pw = &pst[w][0];
  {
    unsigned w0 = pk2_bf16(ad[0], ad[1]), w1 = pk2_bf16(ad[2], ad[3]);
    *(uint2*)(&pw[c * PST + 4 * g]) = make_uint2(w0, w1);
  }

  // ---- PV: P-frag = one b128 read, V-frag = bf16 scalars (no cvt) ----
  // same-wave DS ops complete in order; compiler inserts lgkmcnt waits.
  short8 pa = {0, 0, 0, 0, 0, 0, 0, 0};
  if (g < 2) pa = *(const short8*)(&pw[c * PST + g * 8]);

  f32x4 oacc[4];
#pragma unroll
  for (int nt = 0; nt < 4; nt++) {
    short8 vb = {0, 0, 0, 0, 0, 0, 0, 0};
    if (g < 2) {
#pragma unroll
      for (int j = 0; j < 8; j++)
        vb[j] = (short)vw[(g * 8 + j) * VST + nt * 16 + c];
    }
    f32x4 z = {0.f, 0.f, 0.f, 0.f};
    oacc[nt] = __builtin_amdgcn_mfma_f32_16x16x32_bf16(pa, vb, z, 0, 0, 0);
  }

  float* op = out + (size_t)bh * 1024;
#pragma unroll
  for (int nt = 0; nt < 4; nt++)
#pragma unroll
    for (int t = 0; t < 4; t++)
      op[(4 * g + t) * 64 + nt * 16 + c] = oacc[nt][t];
}

extern "C" void kernel_launch(void* const* d_in, const int* in_sizes, int n_in,
                              void* d_out, int out_size, void* d_ws, size_t ws_size,
                              hipStream_t stream) {
  const float* q = (const float*)d_in[0];
  const float* k = (const float*)d_in[1];
  const float* v = (const float*)d_in[2];
  float* out = (float*)d_out;
  attn_kernel<<<2048, 256, 0, stream>>>(q, k, v, out);
}

// Round 5
// 135.163 us; speedup vs baseline: 1.0102x; 1.0102x over previous
//
#include <hip/hip_runtime.h>
#include <hip/hip_bf16.h>
#include <stdint.h>
#include <stddef.h>

// Attention B=256,H=32,S=16,D=64: softmax(QK^T/sqrt(8) + ones) with JAX
// threefry dropout p=0.3 (key 42), then @V.
// R4: swapped QK^T (S^T = mfma(K,Q)) -> 4-shfl softmax; bf16 LDS staging via
// cvt_pk; no barriers (per-wave LDS); measured <39.8us (2 heads/wave).
// R5: 1 head/wave + 8 waves/SIMD: ~46us. CONCLUSION: TLP inert (convoy),
// ILP depth is the only measured lever (R0 46.6 / R4 <39.8 / R5 46).
// R6: depth-4 pipeline. One wave owns 4 consecutive heads; head h+1 loads +
// threefry mask issued before head h compute -> each head's HBM latency gets
// a full compute-phase shadow. Grid 512 (2 blocks/CU), lb(256,2) for VGPR
// headroom. Per-head math identical to R5 (absmax canary 0.03125).

typedef __attribute__((ext_vector_type(8))) short short8;
typedef __attribute__((ext_vector_type(4))) float f32x4;
typedef __attribute__((ext_vector_type(4))) unsigned int u32x4;

#define VST 68  // V tile row stride (shorts): 8B-aligned rows, reads ~conflict-free
#define PST 24  // P tile row stride (shorts): 16B-aligned b128 frag reads

// packed f32x2 -> bf16x2, RNE via v_cvt_pk_bf16_f32 (compiler-generated)
__device__ __forceinline__ unsigned pk2_bf16(float a, float b) {
  float2 t; t.x = a; t.y = b;
  __hip_bfloat162 h = __float22bfloat162_rn(t);
  unsigned r;
  __builtin_memcpy(&r, &h, 4);
  return r;
}

// JAX threefry2x32, key=(0,42), counter (0, idx); draw = x0^x1. Bit-exact vs
// jax.random.bernoulli(jax.random.key(42), ...) — verified R0 (absmax 0.031).
__device__ __forceinline__ unsigned threefry_bits(unsigned idx) {
  const unsigned k0 = 0u, k1 = 42u;
  const unsigned k2 = k0 ^ k1 ^ 0x1BD11BDAu;
  unsigned x0 = k0;
  unsigned x1 = idx + k1;
#define TF_ROUND(r) { x0 += x1; x1 = (x1 << (r)) | (x1 >> (32 - (r))); x1 ^= x0; }
  TF_ROUND(13) TF_ROUND(15) TF_ROUND(26) TF_ROUND(6)
  x0 += k1; x1 += k2 + 1u;
  TF_ROUND(17) TF_ROUND(29) TF_ROUND(16) TF_ROUND(24)
  x0 += k2; x1 += k0 + 2u;
  TF_ROUND(13) TF_ROUND(15) TF_ROUND(26) TF_ROUND(6)
  x0 += k0; x1 += k1 + 3u;
  TF_ROUND(17) TF_ROUND(29) TF_ROUND(16) TF_ROUND(24)
  x0 += k1; x1 += k2 + 4u;
  TF_ROUND(13) TF_ROUND(15) TF_ROUND(26) TF_ROUND(6)
  x0 += k2; x1 += k0 + 5u;
#undef TF_ROUND
  return x0 ^ x1;
}

// mask for element idx = bh*256 + base + t, t=0..3 (value includes 1/0.7 scale)
__device__ __forceinline__ void drop_mask(int bh, int base, float* m) {
#pragma unroll
  for (int t = 0; t < 4; t++) {
    unsigned idx = ((unsigned)bh << 8) + (unsigned)(base + t);
    unsigned bits = threefry_bits(idx);
    float u = __builtin_bit_cast(float, 0x3F800000u | (bits >> 9)) - 1.0f;
    m[t] = (u < 0.7f) ? (1.0f / 0.7f) : 0.0f;
  }
}

// 8 f32 -> hi/lo bf16 split via cvt_pk pairs (~3 ops/elem vs ~12 bitwise)
__device__ __forceinline__ void cvt_hilo_f4(float4 a, float4 b, short8& hi, short8& lo) {
  float x[8] = {a.x, a.y, a.z, a.w, b.x, b.y, b.z, b.w};
  u32x4 hw, lw;
#pragma unroll
  for (int i = 0; i < 4; i++) {
    float e0 = x[2 * i], e1 = x[2 * i + 1];
    unsigned hp = pk2_bf16(e0, e1);
    float h0 = __builtin_bit_cast(float, hp << 16);
    float h1 = __builtin_bit_cast(float, hp & 0xFFFF0000u);
    unsigned lp = pk2_bf16(e0 - h0, e1 - h1);
    hw[i] = hp; lw[i] = lp;
  }
  hi = __builtin_bit_cast(short8, hw);
  lo = __builtin_bit_cast(short8, lw);
}

__global__ __launch_bounds__(256, 2) void attn_kernel(
    const float* __restrict__ q, const float* __restrict__ k,
    const float* __restrict__ v, float* __restrict__ out) {
  // per-wave LDS, single-buffered across heads (same-wave DS ops complete in
  // order: head h+1 staging writes can't pass head h's PV reads)
  __shared__ __align__(16) unsigned short vst[4][16 * VST];  // 8704 B
  __shared__ __align__(16) unsigned short pst[4][16 * PST];  // 3072 B

  const int lane = threadIdx.x & 63;
  const int w = threadIdx.x >> 6;
  const int base = (blockIdx.x * 4 + w) * 4;  // first of this wave's 4 heads
  const int c = lane & 15;                    // frag row; swapped QK^T: q-row
  const int g = lane >> 4;                    // quad

  float4 qv[2][4], kv[2][4], vt[2][4];
  float m[2][4];

  // ---- prologue: head 0 loads + mask ----
  {
    const float4* qr = (const float4*)(q + (size_t)base * 1024 + c * 64 + g * 8);
    const float4* kr = (const float4*)(k + (size_t)base * 1024 + c * 64 + g * 8);
    qv[0][0] = qr[0]; qv[0][1] = qr[1]; qv[0][2] = qr[8]; qv[0][3] = qr[9];
    kv[0][0] = kr[0]; kv[0][1] = kr[1]; kv[0][2] = kr[8]; kv[0][3] = kr[9];
    const float4* vs = (const float4*)(v + (size_t)base * 1024);
    vt[0][0] = vs[lane]; vt[0][1] = vs[64 + lane];
    vt[0][2] = vs[128 + lane]; vt[0][3] = vs[192 + lane];
    drop_mask(base, (c << 4) + 4 * g, m[0]);
  }

  unsigned short* vw = &vst[w][0];
  unsigned short* pw = &pst[w][0];

#pragma unroll
  for (int h = 0; h < 4; h++) {
    const int b = h & 1, nb = b ^ 1;  // compile-time after full unroll
    const int bh = base + h;

    // ---- issue head h+1 loads + mask (shadowed by head h compute) ----
    if (h < 3) {
      const int bhn = bh + 1;
      const float4* qr = (const float4*)(q + (size_t)bhn * 1024 + c * 64 + g * 8);
      const float4* kr = (const float4*)(k + (size_t)bhn * 1024 + c * 64 + g * 8);
      qv[nb][0] = qr[0]; qv[nb][1] = qr[1]; qv[nb][2] = qr[8]; qv[nb][3] = qr[9];
      kv[nb][0] = kr[0]; kv[nb][1] = kr[1]; kv[nb][2] = kr[8]; kv[nb][3] = kr[9];
      const float4* vs = (const float4*)(v + (size_t)bhn * 1024);
      vt[nb][0] = vs[lane]; vt[nb][1] = vs[64 + lane];
      vt[nb][2] = vs[128 + lane]; vt[nb][3] = vs[192 + lane];
      // data-independent VALU: executes while the loads above are in flight
      drop_mask(bhn, (c << 4) + 4 * g, m[nb]);
    }

    // ---- Q/K hi/lo bf16 split (head h data: loaded one iteration ago) ----
    short8 qhi0, qlo0, qhi1, qlo1, khi0, klo0, khi1, klo1;
    cvt_hilo_f4(qv[b][0], qv[b][1], qhi0, qlo0);
    cvt_hilo_f4(qv[b][2], qv[b][3], qhi1, qlo1);
    cvt_hilo_f4(kv[b][0], kv[b][1], khi0, klo0);
    cvt_hilo_f4(kv[b][2], kv[b][3], khi1, klo1);

    // ---- S^T = K Q^T (swapped operands): hi*hi + lo*hi + hi*lo ----
    // acc[t] = S[c][4g+t] -> q-row c is in-lane across regs t and quads g.
    f32x4 acc = {0.f, 0.f, 0.f, 0.f};
    acc = __builtin_amdgcn_mfma_f32_16x16x32_bf16(khi0, qhi0, acc, 0, 0, 0);
    acc = __builtin_amdgcn_mfma_f32_16x16x32_bf16(khi1, qhi1, acc, 0, 0, 0);
    acc = __builtin_amdgcn_mfma_f32_16x16x32_bf16(klo0, qhi0, acc, 0, 0, 0);
    acc = __builtin_amdgcn_mfma_f32_16x16x32_bf16(klo1, qhi1, acc, 0, 0, 0);
    acc = __builtin_amdgcn_mfma_f32_16x16x32_bf16(khi0, qlo0, acc, 0, 0, 0);
    acc = __builtin_amdgcn_mfma_f32_16x16x32_bf16(khi1, qlo1, acc, 0, 0, 0);

    // ---- row softmax: 3 VALU + 2 shfl for max, same for sum ----
    // +ones mask cancels in softmax.
    const float SCALE = 0.35355339059327373f;
    float sv[4];
#pragma unroll
    for (int t = 0; t < 4; t++) sv[t] = acc[t] * SCALE;
    float mx = fmaxf(fmaxf(sv[0], sv[1]), fmaxf(sv[2], sv[3]));
    mx = fmaxf(mx, __shfl_xor(mx, 16));
    mx = fmaxf(mx, __shfl_xor(mx, 32));
    float p0 = __expf(sv[0] - mx), p1 = __expf(sv[1] - mx);
    float p2v = __expf(sv[2] - mx), p3 = __expf(sv[3] - mx);
    float sum = (p0 + p1) + (p2v + p3);
    sum += __shfl_xor(sum, 16);
    sum += __shfl_xor(sum, 32);
    float rs = 1.0f / sum;
    float ad[4] = {p0 * rs * m[b][0], p1 * rs * m[b][1],
                   p2v * rs * m[b][2], p3 * rs * m[b][3]};

    // ---- stage V as bf16 (cvt_pk at write). lane holds V[4p+g][4c..4c+3] ----
    {
      float4 vv;
      unsigned w0, w1;
      vv = vt[b][0]; w0 = pk2_bf16(vv.x, vv.y); w1 = pk2_bf16(vv.z, vv.w);
      *(uint2*)(&vw[(0 + g) * VST + 4 * c]) = make_uint2(w0, w1);
      vv = vt[b][1]; w0 = pk2_bf16(vv.x, vv.y); w1 = pk2_bf16(vv.z, vv.w);
      *(uint2*)(&vw[(4 + g) * VST + 4 * c]) = make_uint2(w0, w1);
      vv = vt[b][2]; w0 = pk2_bf16(vv.x, vv.y); w1 = pk2_bf16(vv.z, vv.w);
      *(uint2*)(&vw[(8 + g) * VST + 4 * c]) = make_uint2(w0, w1);
      vv = vt[b][3]; w0 = pk2_bf16(vv.x, vv.y); w1 = pk2_bf16(vv.z, vv.w);
      *(uint2*)(&vw[(12 + g) * VST + 4 * c]) = make_uint2(w0, w1);
    }

    // ---- stage P as bf16: one 8B packed write (row c, cols 4g..4g+3) ----
    {
      unsigned w0 = pk2_bf16(ad[0], ad[1]), w1 = pk2_bf16(ad[2], ad[3]);
      *(uint2*)(&pw[c * PST + 4 * g]) = make_uint2(w0, w1);
    }

    // ---- PV: P-frag = one b128 read, V-frag = bf16 scalars (no cvt) ----
    short8 pa = {0, 0, 0, 0, 0, 0, 0, 0};
    if (g < 2) pa = *(const short8*)(&pw[c * PST + g * 8]);

    f32x4 oacc[4];
#pragma unroll
    for (int nt = 0; nt < 4; nt++) {
      short8 vb = {0, 0, 0, 0, 0, 0, 0, 0};
      if (g < 2) {
#pragma unroll
        for (int j = 0; j < 8; j++)
          vb[j] = (short)vw[(g * 8 + j) * VST + nt * 16 + c];
      }
      f32x4 z = {0.f, 0.f, 0.f, 0.f};
      oacc[nt] = __builtin_amdgcn_mfma_f32_16x16x32_bf16(pa, vb, z, 0, 0, 0);
    }

    float* op = out + (size_t)bh * 1024;
#pragma unroll
    for (int nt = 0; nt < 4; nt++)
#pragma unroll
      for (int t = 0; t < 4; t++)
        op[(4 * g + t) * 64 + nt * 16 + c] = oacc[nt][t];
  }
}

extern "C" void kernel_launch(void* const* d_in, const int* in_sizes, int n_in,
                              void* d_out, int out_size, void* d_ws, size_t ws_size,
                              hipStream_t stream) {
  const float* q = (const float*)d_in[0];
  const float* k = (const float*)d_in[1];
  const float* v = (const float*)d_in[2];
  float* out = (float*)d_out;
  attn_kernel<<<512, 256, 0, stream>>>(q, k, v, out);
}